// Round 10
// baseline (914.743 us; speedup 1.0000x reference)
//
#include <hip/hip_runtime.h>
#include <float.h>
#include <stdint.h>

// VectorQuantizer R16: R14 base (best total 736us, GEMM 496us) with ONE
// change: MFMA shape 16x16x32 -> 32x32x16 in vq_gemm.
//  Rationale: 32x32x16 bf16 measures 2382-2495 TF vs 2075 for 16x16x32
//  (~+17% FLOP/cyc) at identical LDS fragment bytes, half the instruction
//  count. Geometry unchanged from R14: 128x128 tile, 512 thr, 8 waves
//  4Mx2N; wave tile 32x64 = 2 x (32x32), acc[2] f32x16 (32 regs, same).
//  Input frag map: idx=lane&31, k=(lane>>5)*8+e (generalizes the proven
//  16x16 map lane&15,(lane>>4)*8+e). C/D map col=lane&31,
//  row=(reg&3)+8*(reg>>2)+4*(lane>>5) [HW-verified m74/m101].
//  Same octet-XOR LDS swizzle (bank-balanced for 32-row reads), same slot
//  partition (slot=ni*2+wn, 64 codes) -> reduce/recheck2/gather verbatim.
//  K-grouping 16 vs 32 shifts distances ~1e-4 << GAP_THRESH=0.02 net.
// d_out = [quantized 16777216 f32][loss 1][indices 65536] ; scratch reuse:
//   pmin2 = 64 slots x float2 x 65536 rows (33.5MB), pidx 16.8MB
// d_ws floats: esq[0,4096) | fcount@4097 | flags@4100 | idx_final@69636 |
//   loss_part@135172 | emb_hi@151556 | emb_lo@675844 | a_hi@1200384 |
//   a_lo@9588992 | keys@17977600 (u64 x 65536) -> end 18108672 fl = 72.4MB

#define DDIM 256
#define KCODES 4096
#define NROWS 65536
#define QSIZE 16777216
#define NSLOT 64
#define NLBLK 16384
#define GAP_THRESH 0.02f

#define O_FCOUNT 4097
#define O_FLAGS 4100
#define O_IDXF 69636
#define O_LPART 135172
#define O_EMBH 151556
#define O_EMBL 675844
#define O_AH 1200384
#define O_AL 9588992
#define O_KEYS 17977600
#define WS_NEED_FLOATS 18108672ull

typedef short bf16x8 __attribute__((ext_vector_type(8)));
typedef float f32x4 __attribute__((ext_vector_type(4)));
typedef float f32x16 __attribute__((ext_vector_type(16)));

__device__ __forceinline__ void gload_lds16(const void* g, void* l) {
    __builtin_amdgcn_global_load_lds(
        (const __attribute__((address_space(1))) void*)g,
        (__attribute__((address_space(3))) void*)l, 16, 0, 0);
}

// ---- esq + emb hi/lo conversion + init (one pass over emb) ----
__global__ __launch_bounds__(64) void esq_conv(const float* __restrict__ emb,
                                               float* __restrict__ ws,
                                               short* __restrict__ eh,
                                               short* __restrict__ el) {
    int c = blockIdx.x, l = threadIdx.x;
    const float4* e4 = (const float4*)(emb + (size_t)c * DDIM);
    float4 v = e4[l];
    float s = v.x * v.x + v.y * v.y + v.z * v.z + v.w * v.w;
    float f[4] = {v.x, v.y, v.z, v.w};
    uint32_t hu[4], lu[4];
#pragma unroll
    for (int k = 0; k < 4; ++k) {
        uint32_t u = __float_as_uint(f[k]);
        uint32_t h = u & 0xFFFF0000u;
        hu[k] = h;
        lu[k] = __float_as_uint(f[k] - __uint_as_float(h));
    }
    uint2 hv, lv;
    hv.x = __builtin_amdgcn_perm(hu[1], hu[0], 0x07060302u);
    hv.y = __builtin_amdgcn_perm(hu[3], hu[2], 0x07060302u);
    lv.x = __builtin_amdgcn_perm(lu[1], lu[0], 0x07060302u);
    lv.y = __builtin_amdgcn_perm(lu[3], lu[2], 0x07060302u);
    *(uint2*)&eh[(size_t)c * DDIM + l * 4] = hv;
    *(uint2*)&el[(size_t)c * DDIM + l * 4] = lv;
#pragma unroll
    for (int off = 32; off >= 1; off >>= 1) s += __shfl_down(s, off);
    if (l == 0) ws[c] = s;
    if (c == 0 && l == 0) ((int*)ws)[O_FCOUNT] = 0;
}

// split fp32 -> (hi bf16, lo bf16), pack 8 elems, write 16B hi + 16B lo
__device__ __forceinline__ void conv8(float4 a, float4 b,
                                      short* __restrict__ dh,
                                      short* __restrict__ dl) {
    float f[8] = {a.x, a.y, a.z, a.w, b.x, b.y, b.z, b.w};
    uint32_t hu[8], lu[8];
#pragma unroll
    for (int k = 0; k < 8; ++k) {
        uint32_t u = __float_as_uint(f[k]);
        uint32_t h = u & 0xFFFF0000u;
        hu[k] = h;
        lu[k] = __float_as_uint(f[k] - __uint_as_float(h));
    }
    uint4 hv, lv;
    hv.x = __builtin_amdgcn_perm(hu[1], hu[0], 0x07060302u);
    hv.y = __builtin_amdgcn_perm(hu[3], hu[2], 0x07060302u);
    hv.z = __builtin_amdgcn_perm(hu[5], hu[4], 0x07060302u);
    hv.w = __builtin_amdgcn_perm(hu[7], hu[6], 0x07060302u);
    lv.x = __builtin_amdgcn_perm(lu[1], lu[0], 0x07060302u);
    lv.y = __builtin_amdgcn_perm(lu[3], lu[2], 0x07060302u);
    lv.z = __builtin_amdgcn_perm(lu[5], lu[4], 0x07060302u);
    lv.w = __builtin_amdgcn_perm(lu[7], lu[6], 0x07060302u);
    *(uint4*)dh = hv;
    *(uint4*)dl = lv;
}

__device__ __forceinline__ void stage8(const float* __restrict__ p,
                                       short* __restrict__ dh,
                                       short* __restrict__ dl) {
    float4 a = *(const float4*)p;
    float4 b = *(const float4*)(p + 4);
    conv8(a, b, dh, dl);
}

// ---- A pre-conversion: inp fp32 -> bf16 hi/lo (memory-bound, ~25us) ----
__global__ __launch_bounds__(256) void inp_conv(const float* __restrict__ inp,
                                                short* __restrict__ ahg,
                                                short* __restrict__ alg) {
    size_t g = (size_t)blockIdx.x * 256 + threadIdx.x;  // granule of 8 elems
    const float* p = inp + g * 8;
    float4 a = *(const float4*)p;
    float4 b = *(const float4*)(p + 4);
    conv8(a, b, ahg + g * 8, alg + g * 8);
}

// ---- main GEMM: 128x128 tile, 512 thr (8 waves 4Mx2N), 32x32x16 MFMA ----
// Wave tile 32x64 = 2 x (32x32). Staging identical R14 (4 gloads/thread,
// 32KB LDS, octet swizzle: row r logical octet o at slot o^((r>>1)&3)).
// Frag read: idx = lane&31, k-octet o = ks*2 + (lane>>5).
__global__ __launch_bounds__(512, 6) void vq_gemm(const short* __restrict__ ahg,
                                                  const short* __restrict__ alg,
                                                  const short* __restrict__ ehg,
                                                  const short* __restrict__ elg,
                                                  const float* __restrict__ esq,
                                                  float2* __restrict__ pmin2,
                                                  int* __restrict__ pidx) {
    __shared__ __align__(16) short Ah[128 * 32];  // 8 KB each, 32 KB total
    __shared__ __align__(16) short Al[128 * 32];
    __shared__ __align__(16) short Bh[128 * 32];
    __shared__ __align__(16) short Bl[128 * 32];

    const int t = threadIdx.x;                    // 0..511
    const int mi = blockIdx.x >> 5, ni = blockIdx.x & 31;
    const size_t row0 = (size_t)mi * 128;
    const int col0 = ni * 128;
    const int lane = t & 63, wave = t >> 6;       // wave 0..7
    const int wm = wave >> 1, wn = wave & 1;      // 4 M-waves x 2 N-waves
    const int r31 = lane & 31, khalf = lane >> 5;

    // staging: 1 granule (8 elems = 16B) per thread per matrix (R13/R14)
    const int r0 = t >> 2, c0 = t & 3;
    const int p0 = c0 ^ ((r0 >> 1) & 3);
    const short* asrch = ahg + (size_t)(row0 + r0) * DDIM + p0 * 8;
    const short* asrcl = alg + (size_t)(row0 + r0) * DDIM + p0 * 8;
    const short* bsrch = ehg + (size_t)(col0 + r0) * DDIM + p0 * 8;
    const short* bsrcl = elg + (size_t)(col0 + r0) * DDIM + p0 * 8;
    const int d0 = t * 8;                         // linear LDS dest

    f32x16 acc[2];
#pragma unroll
    for (int j = 0; j < 2; ++j)
#pragma unroll
        for (int r = 0; r < 16; ++r) acc[j][r] = 0.f;

    // frag addresses (lane-fixed parts)
    const int arow = wm * 32 + r31;
    const int aswz = (arow >> 1) & 3;
    const int brow0 = wn * 64 + r31;              // j adds 32
    const int brow1 = brow0 + 32;
    const int bswz0 = (brow0 >> 1) & 3;
    const int bswz1 = (brow1 >> 1) & 3;

#pragma unroll
    for (int ch = 0; ch < 8; ++ch) {
        __syncthreads();  // prior chunk's LDS reads complete
        gload_lds16(asrch + ch * 32, &Ah[d0]);
        gload_lds16(asrcl + ch * 32, &Al[d0]);
        gload_lds16(bsrch + ch * 32, &Bh[d0]);
        gload_lds16(bsrcl + ch * 32, &Bl[d0]);
        __syncthreads();  // drains vmcnt -> tiles visible

#pragma unroll
        for (int ks = 0; ks < 2; ++ks) {
            const int o = ks * 2 + khalf;         // logical k-octet
            bf16x8 ahf = *(const bf16x8*)&Ah[arow * 32 + ((o ^ aswz) * 8)];
            bf16x8 alf = *(const bf16x8*)&Al[arow * 32 + ((o ^ aswz) * 8)];
            bf16x8 bhf0 = *(const bf16x8*)&Bh[brow0 * 32 + ((o ^ bswz0) * 8)];
            bf16x8 blf0 = *(const bf16x8*)&Bl[brow0 * 32 + ((o ^ bswz0) * 8)];
            bf16x8 bhf1 = *(const bf16x8*)&Bh[brow1 * 32 + ((o ^ bswz1) * 8)];
            bf16x8 blf1 = *(const bf16x8*)&Bl[brow1 * 32 + ((o ^ bswz1) * 8)];
            acc[0] = __builtin_amdgcn_mfma_f32_32x32x16_bf16(ahf, bhf0, acc[0], 0, 0, 0);
            acc[0] = __builtin_amdgcn_mfma_f32_32x32x16_bf16(ahf, blf0, acc[0], 0, 0, 0);
            acc[0] = __builtin_amdgcn_mfma_f32_32x32x16_bf16(alf, bhf0, acc[0], 0, 0, 0);
            acc[1] = __builtin_amdgcn_mfma_f32_32x32x16_bf16(ahf, bhf1, acc[1], 0, 0, 0);
            acc[1] = __builtin_amdgcn_mfma_f32_32x32x16_bf16(ahf, blf1, acc[1], 0, 0, 0);
            acc[1] = __builtin_amdgcn_mfma_f32_32x32x16_bf16(alf, bhf1, acc[1], 0, 0, 0);
        }
    }

    // ---- epilogue: per-wave top-2 over its 64 codes (32x32 C layout) ----
    // value acc[j][r]: row = wm*32 + (r&3)+8*(r>>2)+4*khalf (wave-local),
    // code = col0 + wn*64 + j*32 + r31. Each output row lives entirely in
    // one 32-lane half; shfl_xor offs 1..16 stay within the half.
    float esqv[2];
#pragma unroll
    for (int j = 0; j < 2; ++j) esqv[j] = esq[col0 + wn * 64 + j * 32 + r31];

#pragma unroll
    for (int r = 0; r < 16; ++r) {
        float m1 = FLT_MAX, m2 = FLT_MAX;
        int bi = 0;
#pragma unroll
        for (int j = 0; j < 2; ++j) {
            float d = esqv[j] - 2.0f * acc[j][r];
            int code = col0 + wn * 64 + j * 32 + r31;
            if (d < m1) { m2 = m1; m1 = d; bi = code; }
            else if (d < m2) { m2 = d; }
        }
#pragma unroll
        for (int off = 1; off < 32; off <<= 1) {
            float om1 = __shfl_xor(m1, off);
            float om2 = __shfl_xor(m2, off);
            int obi = __shfl_xor(bi, off);
            bool take = (om1 < m1) || (om1 == m1 && obi < bi);
            if (take) { m2 = fminf(m1, om2); m1 = om1; bi = obi; }
            else      { m2 = fminf(om1, m2); }
        }
        if (r31 == 0) {
            int rg = (int)row0 + wm * 32 + (r & 3) + 8 * (r >> 2) + 4 * khalf;
            int slot = ni * 2 + wn;
            pmin2[(size_t)slot * NROWS + rg] = make_float2(m1, m2);
            pidx[(size_t)slot * NROWS + rg] = bi;
        }
    }
}

// ---- fallback GEMM (R6 verbatim): in-kernel A conversion, small ws ----
__global__ __launch_bounds__(256, 2) void vq_gemm_fb(const float* __restrict__ inp,
                                                     const short* __restrict__ ehg,
                                                     const short* __restrict__ elg,
                                                     const float* __restrict__ esq,
                                                     float2* __restrict__ pmin2,
                                                     int* __restrict__ pidx) {
    __shared__ __align__(16) short Ah[128 * 32];
    __shared__ __align__(16) short Al[128 * 32];
    __shared__ __align__(16) short Bh[128 * 32];
    __shared__ __align__(16) short Bl[128 * 32];

    const int t = threadIdx.x;
    const int mi = blockIdx.x >> 5, ni = blockIdx.x & 31;
    const size_t row0 = (size_t)mi * 128;
    const int col0 = ni * 128;
    const int lane = t & 63, wave = t >> 6;
    const int wm = wave >> 1, wn = wave & 1;
    const int n15 = lane & 15, quad = lane >> 4;
    const int swz = (n15 >> 1) & 3;

    const int ar0 = t >> 2, ac0 = t & 3;
    const int ap0 = ac0 ^ ((ar0 >> 1) & 3);
    const int ar1 = (t + 256) >> 2, ac1 = ac0;
    const int ap1 = ac1 ^ ((ar1 >> 1) & 3);
    const float* asrc0 = inp + (row0 + ar0) * DDIM + ac0 * 8;
    const float* asrc1 = inp + (row0 + ar1) * DDIM + ac1 * 8;
    short* adst0h = &Ah[ar0 * 32 + ap0 * 8];
    short* adst0l = &Al[ar0 * 32 + ap0 * 8];
    short* adst1h = &Ah[ar1 * 32 + ap1 * 8];
    short* adst1l = &Al[ar1 * 32 + ap1 * 8];
    const int br0 = ar0, bp0 = ac0, bk0 = bp0 ^ ((br0 >> 1) & 3);
    const int br1 = ar1, bp1 = ac1, bk1 = bp1 ^ ((br1 >> 1) & 3);
    const short* bsrc0h = ehg + (size_t)(col0 + br0) * DDIM + bk0 * 8;
    const short* bsrc0l = elg + (size_t)(col0 + br0) * DDIM + bk0 * 8;
    const short* bsrc1h = ehg + (size_t)(col0 + br1) * DDIM + bk1 * 8;
    const short* bsrc1l = elg + (size_t)(col0 + br1) * DDIM + bk1 * 8;

    f32x4 acc[4][4];
#pragma unroll
    for (int i = 0; i < 4; ++i)
#pragma unroll
        for (int j = 0; j < 4; ++j) {
            acc[i][j][0] = 0.f; acc[i][j][1] = 0.f;
            acc[i][j][2] = 0.f; acc[i][j][3] = 0.f;
        }

#pragma unroll
    for (int ch = 0; ch < 8; ++ch) {
        __syncthreads();
        gload_lds16(bsrc0h + ch * 32, &Bh[t * 8]);
        gload_lds16(bsrc0l + ch * 32, &Bl[t * 8]);
        gload_lds16(bsrc1h + ch * 32, &Bh[(t + 256) * 8]);
        gload_lds16(bsrc1l + ch * 32, &Bl[(t + 256) * 8]);
        stage8(asrc0 + ch * 32, adst0h, adst0l);
        stage8(asrc1 + ch * 32, adst1h, adst1l);
        __syncthreads();

        bf16x8 ah[4], al[4];
#pragma unroll
        for (int i = 0; i < 4; ++i) {
            int off = (wm * 64 + i * 16 + n15) * 32 + ((quad ^ swz) * 8);
            ah[i] = *(const bf16x8*)&Ah[off];
            al[i] = *(const bf16x8*)&Al[off];
        }
#pragma unroll
        for (int j = 0; j < 4; ++j) {
            int boff = (wn * 64 + j * 16 + n15) * 32 + ((quad ^ swz) * 8);
            bf16x8 bh = *(const bf16x8*)&Bh[boff];
            bf16x8 bl = *(const bf16x8*)&Bl[boff];
#pragma unroll
            for (int i = 0; i < 4; ++i) {
                acc[i][j] = __builtin_amdgcn_mfma_f32_16x16x32_bf16(ah[i], bh, acc[i][j], 0, 0, 0);
                acc[i][j] = __builtin_amdgcn_mfma_f32_16x16x32_bf16(ah[i], bl, acc[i][j], 0, 0, 0);
                acc[i][j] = __builtin_amdgcn_mfma_f32_16x16x32_bf16(al[i], bh, acc[i][j], 0, 0, 0);
            }
        }
    }

    float esqv[4];
#pragma unroll
    for (int j = 0; j < 4; ++j) esqv[j] = esq[col0 + wn * 64 + j * 16 + n15];

#pragma unroll
    for (int i = 0; i < 4; ++i) {
#pragma unroll
        for (int reg = 0; reg < 4; ++reg) {
            float m1 = FLT_MAX, m2 = FLT_MAX;
            int bi = 0;
#pragma unroll
            for (int j = 0; j < 4; ++j) {
                float d = esqv[j] - 2.0f * acc[i][j][reg];
                int code = col0 + wn * 64 + j * 16 + n15;
                if (d < m1) { m2 = m1; m1 = d; bi = code; }
                else if (d < m2) { m2 = d; }
            }
#pragma unroll
            for (int off = 1; off < 16; off <<= 1) {
                float om1 = __shfl_xor(m1, off);
                float om2 = __shfl_xor(m2, off);
                int obi = __shfl_xor(bi, off);
                bool take = (om1 < m1) || (om1 == m1 && obi < bi);
                if (take) { m2 = fminf(m1, om2); m1 = om1; bi = obi; }
                else      { m2 = fminf(om1, m2); }
            }
            if (n15 == 0) {
                int rg = (int)row0 + wm * 64 + i * 16 + quad * 4 + reg;
                int slot = ni * 2 + wn;
                pmin2[(size_t)slot * NROWS + rg] = make_float2(m1, m2);
                pidx[(size_t)slot * NROWS + rg] = bi;
            }
        }
    }
}

// ---- reduce 64 per-wave partials per row; flag near-ties (+key init) ----
__global__ __launch_bounds__(256) void vq_reduce(const float2* __restrict__ pmin2,
                                                 const int* __restrict__ pidx,
                                                 int* __restrict__ idx_final,
                                                 int* __restrict__ flags,
                                                 int* __restrict__ fcount,
                                                 unsigned long long* __restrict__ keys) {
    int row = blockIdx.x * 256 + threadIdx.x;
    float m1 = FLT_MAX, m2 = FLT_MAX;
    int bi = 0;
    for (int nb = 0; nb < NSLOT; ++nb) {
        float2 p = pmin2[(size_t)nb * NROWS + row];
        int pi = pidx[(size_t)nb * NROWS + row];
        if (p.x < m1) { m2 = fminf(m1, p.y); m1 = p.x; bi = pi; }
        else          { m2 = fminf(m2, p.x); }
    }
    idx_final[row] = bi;
    if (m2 - m1 < GAP_THRESH) {
        int s = atomicAdd(fcount, 1);
        flags[s] = row;
        if (keys) keys[s] = 0xFFFFFFFFFFFFFFFFull;
    }
}

// ---- fast fp32 recheck: 16 blocks per flagged row, 1 code/thread ----
__global__ __launch_bounds__(256) void vq_recheck2(const float* __restrict__ inp,
                                                   const float* __restrict__ emb,
                                                   const float* __restrict__ esq,
                                                   const int* __restrict__ flags,
                                                   const int* __restrict__ fcount,
                                                   unsigned long long* __restrict__ keys) {
    __shared__ float4 xs[64];
    __shared__ unsigned long long wbest[4];
    const int t = threadIdx.x;
    const int total = (*fcount) * 16;
    for (int wi = blockIdx.x; wi < total; wi += gridDim.x) {
        const int fi = wi >> 4, cb = wi & 15;
        const int row = flags[fi];
        __syncthreads();
        if (t < 64) xs[t] = ((const float4*)inp)[(size_t)row * 64 + t];
        __syncthreads();
        const int c = cb * 256 + t;
        const float4* e4 = (const float4*)emb + (size_t)c * 64;
        float dot = 0.f;
        for (int d4 = 0; d4 < 64; ++d4) {
            float4 e = e4[d4];
            float4 x = xs[d4];
            dot += e.x * x.x; dot += e.y * x.y;
            dot += e.z * x.z; dot += e.w * x.w;
        }
        float d = esq[c] - 2.0f * dot;
        unsigned u = __float_as_uint(d);
        unsigned skey = (u & 0x80000000u) ? ~u : (u | 0x80000000u);
        unsigned long long k = ((unsigned long long)skey << 32) | (unsigned)c;
#pragma unroll
        for (int off = 1; off < 64; off <<= 1) {
            unsigned long long o = __shfl_xor(k, off);
            if (o < k) k = o;
        }
        if ((t & 63) == 0) wbest[t >> 6] = k;
        __syncthreads();
        if (t == 0) {
            unsigned long long b = wbest[0];
            if (wbest[1] < b) b = wbest[1];
            if (wbest[2] < b) b = wbest[2];
            if (wbest[3] < b) b = wbest[3];
            atomicMin(&keys[fi], b);
        }
    }
}

__global__ __launch_bounds__(256) void vq_unpack(const int* __restrict__ flags,
                                                 const int* __restrict__ fcount,
                                                 const unsigned long long* __restrict__ keys,
                                                 int* __restrict__ idx_final) {
    int i = blockIdx.x * 256 + threadIdx.x;
    if (i < *fcount) idx_final[flags[i]] = (int)(keys[i] & 0xFFFFFFFFull);
}

// ---- original serial recheck (fallback path only) ----
__global__ __launch_bounds__(256) void vq_recheck(const float* __restrict__ inp,
                                                  const float* __restrict__ emb,
                                                  const float* __restrict__ esq,
                                                  const int* __restrict__ flags,
                                                  const int* __restrict__ fcount,
                                                  int* __restrict__ idx_final) {
    __shared__ float4 xs[64];
    __shared__ float sv[4];
    __shared__ int si[4];
    const int t = threadIdx.x;
    const int cnt = *fcount;
    for (int f = blockIdx.x; f < cnt; f += gridDim.x) {
        int row = flags[f];
        __syncthreads();
        if (t < 64) xs[t] = ((const float4*)inp)[(size_t)row * 64 + t];
        __syncthreads();
        float m1 = FLT_MAX;
        int bi = 0x7FFFFFFF;
        for (int cc = 0; cc < 16; ++cc) {
            int c = cc * 256 + t;
            const float4* e4 = (const float4*)emb + (size_t)c * 64;
            float dot = 0.f;
            for (int d4 = 0; d4 < 64; ++d4) {
                float4 e = e4[d4];
                float4 x = xs[d4];
                dot += e.x * x.x; dot += e.y * x.y;
                dot += e.z * x.z; dot += e.w * x.w;
            }
            float d = esq[c] - 2.0f * dot;
            if (d < m1 || (d == m1 && c < bi)) { m1 = d; bi = c; }
        }
#pragma unroll
        for (int off = 1; off < 64; off <<= 1) {
            float om = __shfl_xor(m1, off);
            int ob = __shfl_xor(bi, off);
            if (om < m1 || (om == m1 && ob < bi)) { m1 = om; bi = ob; }
        }
        if ((t & 63) == 0) { sv[t >> 6] = m1; si[t >> 6] = bi; }
        __syncthreads();
        if (t == 0) {
            for (int w = 1; w < 4; ++w)
                if (sv[w] < m1 || (sv[w] == m1 && si[w] < bi)) { m1 = sv[w]; bi = si[w]; }
            idx_final[row] = bi;
        }
    }
}

// ---- gather quantized, write indices, per-block loss partial ----
__global__ __launch_bounds__(256) void vq_gather(const float* __restrict__ inp,
                                                 const float* __restrict__ emb,
                                                 const int* __restrict__ idx_final,
                                                 float* __restrict__ out,
                                                 float* __restrict__ loss_part) {
    __shared__ float wsum[4];
    size_t gid = (size_t)blockIdx.x * 256 + threadIdx.x;
    int row = (int)(gid >> 6), c4 = (int)(gid & 63);
    int k = idx_final[row];
    float4 e = ((const float4*)emb)[(size_t)k * 64 + c4];
    float4 x = ((const float4*)inp)[gid];
    ((float4*)out)[gid] = e;
    float dx = e.x - x.x, dy = e.y - x.y, dz = e.z - x.z, dw = e.w - x.w;
    float ls = dx * dx + dy * dy + dz * dz + dw * dw;
#pragma unroll
    for (int off = 32; off >= 1; off >>= 1) ls += __shfl_down(ls, off);
    if ((threadIdx.x & 63) == 0) wsum[threadIdx.x >> 6] = ls;
    if (c4 == 0) out[(size_t)QSIZE + 1 + row] = (float)k;
    __syncthreads();
    if (threadIdx.x == 0)
        loss_part[blockIdx.x] = wsum[0] + wsum[1] + wsum[2] + wsum[3];
}

__global__ __launch_bounds__(256) void loss_kernel(const float* __restrict__ loss_part,
                                                   float* __restrict__ out) {
    __shared__ float sw[4];
    int t = threadIdx.x;
    float s = 0.0f;
    for (int i = t; i < NLBLK; i += 256) s += loss_part[i];
#pragma unroll
    for (int off = 32; off >= 1; off >>= 1) s += __shfl_down(s, off);
    if ((t & 63) == 0) sw[t >> 6] = s;
    __syncthreads();
    if (t == 0)
        out[QSIZE] = (sw[0] + sw[1] + sw[2] + sw[3]) * (1.0f / 16777216.0f);
}

extern "C" void kernel_launch(void* const* d_in, const int* in_sizes, int n_in,
                              void* d_out, int out_size, void* d_ws, size_t ws_size,
                              hipStream_t stream) {
    const float* inp = (const float*)d_in[0];
    const float* emb = (const float*)d_in[1];
    float* out = (float*)d_out;
    float* ws = (float*)d_ws;

    float* esq = ws;
    int* fcount = (int*)ws + O_FCOUNT;
    int* flags = (int*)ws + O_FLAGS;
    int* idx_final = (int*)ws + O_IDXF;
    float* loss_part = ws + O_LPART;
    short* eh = (short*)(ws + O_EMBH);
    short* el = (short*)(ws + O_EMBL);

    // partials in d_out's quantized region (overwritten by vq_gather)
    float2* pmin2 = (float2*)out;                 // [0, 8388608) floats
    int* pidx = (int*)out + 8388608;              // [8388608, 12582912)

    hipLaunchKernelGGL(esq_conv, dim3(KCODES), dim3(64), 0, stream, emb, ws, eh, el);

    if (ws_size >= WS_NEED_FLOATS * 4ull) {
        short* ah = (short*)(ws + O_AH);
        short* al = (short*)(ws + O_AL);
        unsigned long long* keys = (unsigned long long*)(ws + O_KEYS);
        hipLaunchKernelGGL(inp_conv, dim3(8192), dim3(256), 0, stream, inp, ah, al);
        hipLaunchKernelGGL(vq_gemm, dim3((NROWS / 128) * 32), dim3(512), 0, stream,
                           ah, al, eh, el, esq, pmin2, pidx);
        hipLaunchKernelGGL(vq_reduce, dim3(NROWS / 256), dim3(256), 0, stream,
                           pmin2, pidx, idx_final, flags, fcount, keys);
        hipLaunchKernelGGL(vq_recheck2, dim3(8192), dim3(256), 0, stream,
                           inp, emb, esq, flags, fcount, keys);
        hipLaunchKernelGGL(vq_unpack, dim3(NROWS / 256), dim3(256), 0, stream,
                           flags, fcount, keys, idx_final);
    } else {
        hipLaunchKernelGGL(vq_gemm_fb, dim3((NROWS / 128) * 32), dim3(256), 0, stream,
                           inp, eh, el, esq, pmin2, pidx);
        hipLaunchKernelGGL(vq_reduce, dim3(NROWS / 256), dim3(256), 0, stream,
                           pmin2, pidx, idx_final, flags, fcount,
                           (unsigned long long*)nullptr);
        hipLaunchKernelGGL(vq_recheck, dim3(256), dim3(256), 0, stream,
                           inp, emb, esq, flags, fcount, idx_final);
    }

    hipLaunchKernelGGL(vq_gather, dim3(NLBLK), dim3(256), 0, stream,
                       inp, emb, idx_final, out, loss_part);
    hipLaunchKernelGGL(loss_kernel, dim3(1), dim3(256), 0, stream, loss_part, out);
}

// Round 11
// 673.482 us; speedup vs baseline: 1.3582x; 1.3582x over previous
//
#include <hip/hip_runtime.h>
#include <float.h>
#include <stdint.h>

// VectorQuantizer R17: GEMM reverted to R14 (proven 496us, 0 conflicts;
// R16's 32x32x16 swap hit 5e7 LDS bank conflicts -> 734us, reverted) +
// ONE change: vq_recheck2 batches 4 flagged rows per block iteration.
//  Recheck cost model: each (row, code-block) pair re-reads 256KB emb from
//  L2; fcount~1-2k -> ~5GB L2 traffic ~ 150us (the unaccounted tail of
//  R14's 736). Batching 4 rows amortizes emb reads 4x -> ~40us.
//  Per-row dot accumulation order unchanged (bit-identical d); per-row
//  sortable-key atomicMin unchanged (deterministic, exact tie rule).
// d_out = [quantized 16777216 f32][loss 1][indices 65536] ; scratch reuse:
//   pmin2 = 64 slots x float2 x 65536 rows (33.5MB), pidx 16.8MB
// d_ws floats: esq[0,4096) | fcount@4097 | flags@4100 | idx_final@69636 |
//   loss_part@135172 | emb_hi@151556 | emb_lo@675844 | a_hi@1200384 |
//   a_lo@9588992 | keys@17977600 (u64 x 65536) -> end 18108672 fl = 72.4MB

#define DDIM 256
#define KCODES 4096
#define NROWS 65536
#define QSIZE 16777216
#define NSLOT 64
#define NLBLK 16384
#define GAP_THRESH 0.02f

#define O_FCOUNT 4097
#define O_FLAGS 4100
#define O_IDXF 69636
#define O_LPART 135172
#define O_EMBH 151556
#define O_EMBL 675844
#define O_AH 1200384
#define O_AL 9588992
#define O_KEYS 17977600
#define WS_NEED_FLOATS 18108672ull

typedef short bf16x8 __attribute__((ext_vector_type(8)));
typedef float f32x4 __attribute__((ext_vector_type(4)));

__device__ __forceinline__ void gload_lds16(const void* g, void* l) {
    __builtin_amdgcn_global_load_lds(
        (const __attribute__((address_space(1))) void*)g,
        (__attribute__((address_space(3))) void*)l, 16, 0, 0);
}

// ---- esq + emb hi/lo conversion + init (one pass over emb) ----
__global__ __launch_bounds__(64) void esq_conv(const float* __restrict__ emb,
                                               float* __restrict__ ws,
                                               short* __restrict__ eh,
                                               short* __restrict__ el) {
    int c = blockIdx.x, l = threadIdx.x;
    const float4* e4 = (const float4*)(emb + (size_t)c * DDIM);
    float4 v = e4[l];
    float s = v.x * v.x + v.y * v.y + v.z * v.z + v.w * v.w;
    float f[4] = {v.x, v.y, v.z, v.w};
    uint32_t hu[4], lu[4];
#pragma unroll
    for (int k = 0; k < 4; ++k) {
        uint32_t u = __float_as_uint(f[k]);
        uint32_t h = u & 0xFFFF0000u;
        hu[k] = h;
        lu[k] = __float_as_uint(f[k] - __uint_as_float(h));
    }
    uint2 hv, lv;
    hv.x = __builtin_amdgcn_perm(hu[1], hu[0], 0x07060302u);
    hv.y = __builtin_amdgcn_perm(hu[3], hu[2], 0x07060302u);
    lv.x = __builtin_amdgcn_perm(lu[1], lu[0], 0x07060302u);
    lv.y = __builtin_amdgcn_perm(lu[3], lu[2], 0x07060302u);
    *(uint2*)&eh[(size_t)c * DDIM + l * 4] = hv;
    *(uint2*)&el[(size_t)c * DDIM + l * 4] = lv;
#pragma unroll
    for (int off = 32; off >= 1; off >>= 1) s += __shfl_down(s, off);
    if (l == 0) ws[c] = s;
    if (c == 0 && l == 0) ((int*)ws)[O_FCOUNT] = 0;
}

// split fp32 -> (hi bf16, lo bf16), pack 8 elems, write 16B hi + 16B lo
__device__ __forceinline__ void conv8(float4 a, float4 b,
                                      short* __restrict__ dh,
                                      short* __restrict__ dl) {
    float f[8] = {a.x, a.y, a.z, a.w, b.x, b.y, b.z, b.w};
    uint32_t hu[8], lu[8];
#pragma unroll
    for (int k = 0; k < 8; ++k) {
        uint32_t u = __float_as_uint(f[k]);
        uint32_t h = u & 0xFFFF0000u;
        hu[k] = h;
        lu[k] = __float_as_uint(f[k] - __uint_as_float(h));
    }
    uint4 hv, lv;
    hv.x = __builtin_amdgcn_perm(hu[1], hu[0], 0x07060302u);
    hv.y = __builtin_amdgcn_perm(hu[3], hu[2], 0x07060302u);
    hv.z = __builtin_amdgcn_perm(hu[5], hu[4], 0x07060302u);
    hv.w = __builtin_amdgcn_perm(hu[7], hu[6], 0x07060302u);
    lv.x = __builtin_amdgcn_perm(lu[1], lu[0], 0x07060302u);
    lv.y = __builtin_amdgcn_perm(lu[3], lu[2], 0x07060302u);
    lv.z = __builtin_amdgcn_perm(lu[5], lu[4], 0x07060302u);
    lv.w = __builtin_amdgcn_perm(lu[7], lu[6], 0x07060302u);
    *(uint4*)dh = hv;
    *(uint4*)dl = lv;
}

__device__ __forceinline__ void stage8(const float* __restrict__ p,
                                       short* __restrict__ dh,
                                       short* __restrict__ dl) {
    float4 a = *(const float4*)p;
    float4 b = *(const float4*)(p + 4);
    conv8(a, b, dh, dl);
}

// ---- A pre-conversion: inp fp32 -> bf16 hi/lo (memory-bound, ~25us) ----
__global__ __launch_bounds__(256) void inp_conv(const float* __restrict__ inp,
                                                short* __restrict__ ahg,
                                                short* __restrict__ alg) {
    size_t g = (size_t)blockIdx.x * 256 + threadIdx.x;  // granule of 8 elems
    const float* p = inp + g * 8;
    float4 a = *(const float4*)p;
    float4 b = *(const float4*)(p + 4);
    conv8(a, b, ahg + g * 8, alg + g * 8);
}

// ---- main GEMM: 128x128 tile, 512 thr (8 waves 4Mx2N), 8 chunks ----
// R14 verbatim (proven 496us / 0 bank conflicts, measured twice).
__global__ __launch_bounds__(512, 6) void vq_gemm(const short* __restrict__ ahg,
                                                  const short* __restrict__ alg,
                                                  const short* __restrict__ ehg,
                                                  const short* __restrict__ elg,
                                                  const float* __restrict__ esq,
                                                  float2* __restrict__ pmin2,
                                                  int* __restrict__ pidx) {
    __shared__ __align__(16) short Ah[128 * 32];  // 8 KB each, 32 KB total
    __shared__ __align__(16) short Al[128 * 32];
    __shared__ __align__(16) short Bh[128 * 32];
    __shared__ __align__(16) short Bl[128 * 32];

    const int t = threadIdx.x;                    // 0..511
    const int mi = blockIdx.x >> 5, ni = blockIdx.x & 31;
    const size_t row0 = (size_t)mi * 128;
    const int col0 = ni * 128;
    const int lane = t & 63, wave = t >> 6;       // wave 0..7
    const int wm = wave >> 1, wn = wave & 1;      // 4 M-waves x 2 N-waves
    const int n15 = lane & 15, quad = lane >> 4;
    const int swz = (n15 >> 1) & 3;

    // staging: 1 granule (8 elems = 16B) per thread per matrix
    const int r0 = t >> 2, c0 = t & 3;
    const int p0 = c0 ^ ((r0 >> 1) & 3);
    const short* asrch = ahg + (size_t)(row0 + r0) * DDIM + p0 * 8;
    const short* asrcl = alg + (size_t)(row0 + r0) * DDIM + p0 * 8;
    const short* bsrch = ehg + (size_t)(col0 + r0) * DDIM + p0 * 8;
    const short* bsrcl = elg + (size_t)(col0 + r0) * DDIM + p0 * 8;
    const int d0 = t * 8;                         // linear LDS dest

    f32x4 acc[2][4];
#pragma unroll
    for (int i = 0; i < 2; ++i)
#pragma unroll
        for (int j = 0; j < 4; ++j) {
            acc[i][j][0] = 0.f; acc[i][j][1] = 0.f;
            acc[i][j][2] = 0.f; acc[i][j][3] = 0.f;
        }

#pragma unroll
    for (int ch = 0; ch < 8; ++ch) {
        __syncthreads();  // prior chunk's LDS reads complete
        gload_lds16(asrch + ch * 32, &Ah[d0]);
        gload_lds16(asrcl + ch * 32, &Al[d0]);
        gload_lds16(bsrch + ch * 32, &Bh[d0]);
        gload_lds16(bsrcl + ch * 32, &Bl[d0]);
        __syncthreads();  // drains vmcnt -> tiles visible

        bf16x8 ah[2], al[2];
#pragma unroll
        for (int i = 0; i < 2; ++i) {
            int off = (wm * 32 + i * 16 + n15) * 32 + ((quad ^ swz) * 8);
            ah[i] = *(const bf16x8*)&Ah[off];
            al[i] = *(const bf16x8*)&Al[off];
        }
#pragma unroll
        for (int j = 0; j < 4; ++j) {
            int boff = (wn * 64 + j * 16 + n15) * 32 + ((quad ^ swz) * 8);
            bf16x8 bh = *(const bf16x8*)&Bh[boff];
            bf16x8 bl = *(const bf16x8*)&Bl[boff];
#pragma unroll
            for (int i = 0; i < 2; ++i) {
                acc[i][j] = __builtin_amdgcn_mfma_f32_16x16x32_bf16(ah[i], bh, acc[i][j], 0, 0, 0);
                acc[i][j] = __builtin_amdgcn_mfma_f32_16x16x32_bf16(ah[i], bl, acc[i][j], 0, 0, 0);
                acc[i][j] = __builtin_amdgcn_mfma_f32_16x16x32_bf16(al[i], bh, acc[i][j], 0, 0, 0);
            }
        }
    }

    // ---- epilogue: per-wave top-2 over its 64 codes (R4 semantics) ----
    float esqv[4];
#pragma unroll
    for (int j = 0; j < 4; ++j) esqv[j] = esq[col0 + wn * 64 + j * 16 + n15];

#pragma unroll
    for (int i = 0; i < 2; ++i) {
#pragma unroll
        for (int reg = 0; reg < 4; ++reg) {
            float m1 = FLT_MAX, m2 = FLT_MAX;
            int bi = 0;
#pragma unroll
            for (int j = 0; j < 4; ++j) {
                float d = esqv[j] - 2.0f * acc[i][j][reg];
                int code = col0 + wn * 64 + j * 16 + n15;
                if (d < m1) { m2 = m1; m1 = d; bi = code; }
                else if (d < m2) { m2 = d; }
            }
#pragma unroll
            for (int off = 1; off < 16; off <<= 1) {
                float om1 = __shfl_xor(m1, off);
                float om2 = __shfl_xor(m2, off);
                int obi = __shfl_xor(bi, off);
                bool take = (om1 < m1) || (om1 == m1 && obi < bi);
                if (take) { m2 = fminf(m1, om2); m1 = om1; bi = obi; }
                else      { m2 = fminf(om1, m2); }
            }
            if (n15 == 0) {
                int rg = (int)row0 + wm * 32 + i * 16 + quad * 4 + reg;
                int slot = ni * 2 + wn;
                pmin2[(size_t)slot * NROWS + rg] = make_float2(m1, m2);
                pidx[(size_t)slot * NROWS + rg] = bi;
            }
        }
    }
}

// ---- fallback GEMM (R6 verbatim): in-kernel A conversion, small ws ----
__global__ __launch_bounds__(256, 2) void vq_gemm_fb(const float* __restrict__ inp,
                                                     const short* __restrict__ ehg,
                                                     const short* __restrict__ elg,
                                                     const float* __restrict__ esq,
                                                     float2* __restrict__ pmin2,
                                                     int* __restrict__ pidx) {
    __shared__ __align__(16) short Ah[128 * 32];
    __shared__ __align__(16) short Al[128 * 32];
    __shared__ __align__(16) short Bh[128 * 32];
    __shared__ __align__(16) short Bl[128 * 32];

    const int t = threadIdx.x;
    const int mi = blockIdx.x >> 5, ni = blockIdx.x & 31;
    const size_t row0 = (size_t)mi * 128;
    const int col0 = ni * 128;
    const int lane = t & 63, wave = t >> 6;
    const int wm = wave >> 1, wn = wave & 1;
    const int n15 = lane & 15, quad = lane >> 4;
    const int swz = (n15 >> 1) & 3;

    const int ar0 = t >> 2, ac0 = t & 3;
    const int ap0 = ac0 ^ ((ar0 >> 1) & 3);
    const int ar1 = (t + 256) >> 2, ac1 = ac0;
    const int ap1 = ac1 ^ ((ar1 >> 1) & 3);
    const float* asrc0 = inp + (row0 + ar0) * DDIM + ac0 * 8;
    const float* asrc1 = inp + (row0 + ar1) * DDIM + ac1 * 8;
    short* adst0h = &Ah[ar0 * 32 + ap0 * 8];
    short* adst0l = &Al[ar0 * 32 + ap0 * 8];
    short* adst1h = &Ah[ar1 * 32 + ap1 * 8];
    short* adst1l = &Al[ar1 * 32 + ap1 * 8];
    const int br0 = ar0, bp0 = ac0, bk0 = bp0 ^ ((br0 >> 1) & 3);
    const int br1 = ar1, bp1 = ac1, bk1 = bp1 ^ ((br1 >> 1) & 3);
    const short* bsrc0h = ehg + (size_t)(col0 + br0) * DDIM + bk0 * 8;
    const short* bsrc0l = elg + (size_t)(col0 + br0) * DDIM + bk0 * 8;
    const short* bsrc1h = ehg + (size_t)(col0 + br1) * DDIM + bk1 * 8;
    const short* bsrc1l = elg + (size_t)(col0 + br1) * DDIM + bk1 * 8;

    f32x4 acc[4][4];
#pragma unroll
    for (int i = 0; i < 4; ++i)
#pragma unroll
        for (int j = 0; j < 4; ++j) {
            acc[i][j][0] = 0.f; acc[i][j][1] = 0.f;
            acc[i][j][2] = 0.f; acc[i][j][3] = 0.f;
        }

#pragma unroll
    for (int ch = 0; ch < 8; ++ch) {
        __syncthreads();
        gload_lds16(bsrc0h + ch * 32, &Bh[t * 8]);
        gload_lds16(bsrc0l + ch * 32, &Bl[t * 8]);
        gload_lds16(bsrc1h + ch * 32, &Bh[(t + 256) * 8]);
        gload_lds16(bsrc1l + ch * 32, &Bl[(t + 256) * 8]);
        stage8(asrc0 + ch * 32, adst0h, adst0l);
        stage8(asrc1 + ch * 32, adst1h, adst1l);
        __syncthreads();

        bf16x8 ah[4], al[4];
#pragma unroll
        for (int i = 0; i < 4; ++i) {
            int off = (wm * 64 + i * 16 + n15) * 32 + ((quad ^ swz) * 8);
            ah[i] = *(const bf16x8*)&Ah[off];
            al[i] = *(const bf16x8*)&Al[off];
        }
#pragma unroll
        for (int j = 0; j < 4; ++j) {
            int boff = (wn * 64 + j * 16 + n15) * 32 + ((quad ^ swz) * 8);
            bf16x8 bh = *(const bf16x8*)&Bh[boff];
            bf16x8 bl = *(const bf16x8*)&Bl[boff];
#pragma unroll
            for (int i = 0; i < 4; ++i) {
                acc[i][j] = __builtin_amdgcn_mfma_f32_16x16x32_bf16(ah[i], bh, acc[i][j], 0, 0, 0);
                acc[i][j] = __builtin_amdgcn_mfma_f32_16x16x32_bf16(ah[i], bl, acc[i][j], 0, 0, 0);
                acc[i][j] = __builtin_amdgcn_mfma_f32_16x16x32_bf16(al[i], bh, acc[i][j], 0, 0, 0);
            }
        }
    }

    float esqv[4];
#pragma unroll
    for (int j = 0; j < 4; ++j) esqv[j] = esq[col0 + wn * 64 + j * 16 + n15];

#pragma unroll
    for (int i = 0; i < 4; ++i) {
#pragma unroll
        for (int reg = 0; reg < 4; ++reg) {
            float m1 = FLT_MAX, m2 = FLT_MAX;
            int bi = 0;
#pragma unroll
            for (int j = 0; j < 4; ++j) {
                float d = esqv[j] - 2.0f * acc[i][j][reg];
                int code = col0 + wn * 64 + j * 16 + n15;
                if (d < m1) { m2 = m1; m1 = d; bi = code; }
                else if (d < m2) { m2 = d; }
            }
#pragma unroll
            for (int off = 1; off < 16; off <<= 1) {
                float om1 = __shfl_xor(m1, off);
                float om2 = __shfl_xor(m2, off);
                int obi = __shfl_xor(bi, off);
                bool take = (om1 < m1) || (om1 == m1 && obi < bi);
                if (take) { m2 = fminf(m1, om2); m1 = om1; bi = obi; }
                else      { m2 = fminf(om1, m2); }
            }
            if (n15 == 0) {
                int rg = (int)row0 + wm * 64 + i * 16 + quad * 4 + reg;
                int slot = ni * 2 + wn;
                pmin2[(size_t)slot * NROWS + rg] = make_float2(m1, m2);
                pidx[(size_t)slot * NROWS + rg] = bi;
            }
        }
    }
}

// ---- reduce 64 per-wave partials per row; flag near-ties (+key init) ----
__global__ __launch_bounds__(256) void vq_reduce(const float2* __restrict__ pmin2,
                                                 const int* __restrict__ pidx,
                                                 int* __restrict__ idx_final,
                                                 int* __restrict__ flags,
                                                 int* __restrict__ fcount,
                                                 unsigned long long* __restrict__ keys) {
    int row = blockIdx.x * 256 + threadIdx.x;
    float m1 = FLT_MAX, m2 = FLT_MAX;
    int bi = 0;
    for (int nb = 0; nb < NSLOT; ++nb) {
        float2 p = pmin2[(size_t)nb * NROWS + row];
        int pi = pidx[(size_t)nb * NROWS + row];
        if (p.x < m1) { m2 = fminf(m1, p.y); m1 = p.x; bi = pi; }
        else          { m2 = fminf(m2, p.x); }
    }
    idx_final[row] = bi;
    if (m2 - m1 < GAP_THRESH) {
        int s = atomicAdd(fcount, 1);
        flags[s] = row;
        if (keys) keys[s] = 0xFFFFFFFFFFFFFFFFull;
    }
}

// ---- fast fp32 recheck: 4 rows batched per block iteration, 1 code/thr ----
// emb block (256KB) is read ONCE per 4 rows (was once per row) -> L2
// traffic /4. Per-row dot order identical to original recheck
// (bit-identical d); per-row sortable-key atomicMin (exact tie rule).
__global__ __launch_bounds__(256) void vq_recheck2(const float* __restrict__ inp,
                                                   const float* __restrict__ emb,
                                                   const float* __restrict__ esq,
                                                   const int* __restrict__ flags,
                                                   const int* __restrict__ fcount,
                                                   unsigned long long* __restrict__ keys) {
    __shared__ float4 xs[4][64];
    __shared__ unsigned long long wbest[4][4];   // [wave][row-in-group]
    const int t = threadIdx.x;
    const int cnt = *fcount;
    const int ngrp = (cnt + 3) >> 2;
    const int total = ngrp * 16;
    for (int wi = blockIdx.x; wi < total; wi += gridDim.x) {
        const int gi = wi >> 4, cb = wi & 15;
        const int base = gi * 4;
        const int nr = (cnt - base < 4) ? (cnt - base) : 4;
        __syncthreads();
        {
            int rr = t >> 6, l = t & 63;          // 4 rows x 64 lanes = 256
            if (rr < nr)
                xs[rr][l] = ((const float4*)inp)[(size_t)flags[base + rr] * 64 + l];
        }
        __syncthreads();
        const int c = cb * 256 + t;
        const float4* e4 = (const float4*)emb + (size_t)c * 64;
        float dot0 = 0.f, dot1 = 0.f, dot2 = 0.f, dot3 = 0.f;
        for (int d4 = 0; d4 < 64; ++d4) {
            float4 e = e4[d4];
            float4 x0 = xs[0][d4];
            float4 x1 = xs[1][d4];
            float4 x2 = xs[2][d4];
            float4 x3 = xs[3][d4];
            dot0 += e.x * x0.x; dot0 += e.y * x0.y; dot0 += e.z * x0.z; dot0 += e.w * x0.w;
            dot1 += e.x * x1.x; dot1 += e.y * x1.y; dot1 += e.z * x1.z; dot1 += e.w * x1.w;
            dot2 += e.x * x2.x; dot2 += e.y * x2.y; dot2 += e.z * x2.z; dot2 += e.w * x2.w;
            dot3 += e.x * x3.x; dot3 += e.y * x3.y; dot3 += e.z * x3.z; dot3 += e.w * x3.w;
        }
        float dts[4] = {dot0, dot1, dot2, dot3};
        const float ec = esq[c];
#pragma unroll
        for (int rr = 0; rr < 4; ++rr) {
            float d = ec - 2.0f * dts[rr];
            unsigned u = __float_as_uint(d);
            unsigned skey = (u & 0x80000000u) ? ~u : (u | 0x80000000u);
            unsigned long long k = ((unsigned long long)skey << 32) | (unsigned)c;
#pragma unroll
            for (int off = 1; off < 64; off <<= 1) {
                unsigned long long o = __shfl_xor(k, off);
                if (o < k) k = o;
            }
            if ((t & 63) == 0) wbest[t >> 6][rr] = k;
        }
        __syncthreads();
        if (t < nr) {
            unsigned long long b = wbest[0][t];
            if (wbest[1][t] < b) b = wbest[1][t];
            if (wbest[2][t] < b) b = wbest[2][t];
            if (wbest[3][t] < b) b = wbest[3][t];
            atomicMin(&keys[base + t], b);
        }
    }
}

__global__ __launch_bounds__(256) void vq_unpack(const int* __restrict__ flags,
                                                 const int* __restrict__ fcount,
                                                 const unsigned long long* __restrict__ keys,
                                                 int* __restrict__ idx_final) {
    int i = blockIdx.x * 256 + threadIdx.x;
    if (i < *fcount) idx_final[flags[i]] = (int)(keys[i] & 0xFFFFFFFFull);
}

// ---- original serial recheck (fallback path only) ----
__global__ __launch_bounds__(256) void vq_recheck(const float* __restrict__ inp,
                                                  const float* __restrict__ emb,
                                                  const float* __restrict__ esq,
                                                  const int* __restrict__ flags,
                                                  const int* __restrict__ fcount,
                                                  int* __restrict__ idx_final) {
    __shared__ float4 xs[64];
    __shared__ float sv[4];
    __shared__ int si[4];
    const int t = threadIdx.x;
    const int cnt = *fcount;
    for (int f = blockIdx.x; f < cnt; f += gridDim.x) {
        int row = flags[f];
        __syncthreads();
        if (t < 64) xs[t] = ((const float4*)inp)[(size_t)row * 64 + t];
        __syncthreads();
        float m1 = FLT_MAX;
        int bi = 0x7FFFFFFF;
        for (int cc = 0; cc < 16; ++cc) {
            int c = cc * 256 + t;
            const float4* e4 = (const float4*)emb + (size_t)c * 64;
            float dot = 0.f;
            for (int d4 = 0; d4 < 64; ++d4) {
                float4 e = e4[d4];
                float4 x = xs[d4];
                dot += e.x * x.x; dot += e.y * x.y;
                dot += e.z * x.z; dot += e.w * x.w;
            }
            float d = esq[c] - 2.0f * dot;
            if (d < m1 || (d == m1 && c < bi)) { m1 = d; bi = c; }
        }
#pragma unroll
        for (int off = 1; off < 64; off <<= 1) {
            float om = __shfl_xor(m1, off);
            int ob = __shfl_xor(bi, off);
            if (om < m1 || (om == m1 && ob < bi)) { m1 = om; bi = ob; }
        }
        if ((t & 63) == 0) { sv[t >> 6] = m1; si[t >> 6] = bi; }
        __syncthreads();
        if (t == 0) {
            for (int w = 1; w < 4; ++w)
                if (sv[w] < m1 || (sv[w] == m1 && si[w] < bi)) { m1 = sv[w]; bi = si[w]; }
            idx_final[row] = bi;
        }
    }
}

// ---- gather quantized, write indices, per-block loss partial ----
__global__ __launch_bounds__(256) void vq_gather(const float* __restrict__ inp,
                                                 const float* __restrict__ emb,
                                                 const int* __restrict__ idx_final,
                                                 float* __restrict__ out,
                                                 float* __restrict__ loss_part) {
    __shared__ float wsum[4];
    size_t gid = (size_t)blockIdx.x * 256 + threadIdx.x;
    int row = (int)(gid >> 6), c4 = (int)(gid & 63);
    int k = idx_final[row];
    float4 e = ((const float4*)emb)[(size_t)k * 64 + c4];
    float4 x = ((const float4*)inp)[gid];
    ((float4*)out)[gid] = e;
    float dx = e.x - x.x, dy = e.y - x.y, dz = e.z - x.z, dw = e.w - x.w;
    float ls = dx * dx + dy * dy + dz * dz + dw * dw;
#pragma unroll
    for (int off = 32; off >= 1; off >>= 1) ls += __shfl_down(ls, off);
    if ((threadIdx.x & 63) == 0) wsum[threadIdx.x >> 6] = ls;
    if (c4 == 0) out[(size_t)QSIZE + 1 + row] = (float)k;
    __syncthreads();
    if (threadIdx.x == 0)
        loss_part[blockIdx.x] = wsum[0] + wsum[1] + wsum[2] + wsum[3];
}

__global__ __launch_bounds__(256) void loss_kernel(const float* __restrict__ loss_part,
                                                   float* __restrict__ out) {
    __shared__ float sw[4];
    int t = threadIdx.x;
    float s = 0.0f;
    for (int i = t; i < NLBLK; i += 256) s += loss_part[i];
#pragma unroll
    for (int off = 32; off >= 1; off >>= 1) s += __shfl_down(s, off);
    if ((t & 63) == 0) sw[t >> 6] = s;
    __syncthreads();
    if (t == 0)
        out[QSIZE] = (sw[0] + sw[1] + sw[2] + sw[3]) * (1.0f / 16777216.0f);
}

extern "C" void kernel_launch(void* const* d_in, const int* in_sizes, int n_in,
                              void* d_out, int out_size, void* d_ws, size_t ws_size,
                              hipStream_t stream) {
    const float* inp = (const float*)d_in[0];
    const float* emb = (const float*)d_in[1];
    float* out = (float*)d_out;
    float* ws = (float*)d_ws;

    float* esq = ws;
    int* fcount = (int*)ws + O_FCOUNT;
    int* flags = (int*)ws + O_FLAGS;
    int* idx_final = (int*)ws + O_IDXF;
    float* loss_part = ws + O_LPART;
    short* eh = (short*)(ws + O_EMBH);
    short* el = (short*)(ws + O_EMBL);

    // partials in d_out's quantized region (overwritten by vq_gather)
    float2* pmin2 = (float2*)out;                 // [0, 8388608) floats
    int* pidx = (int*)out + 8388608;              // [8388608, 12582912)

    hipLaunchKernelGGL(esq_conv, dim3(KCODES), dim3(64), 0, stream, emb, ws, eh, el);

    if (ws_size >= WS_NEED_FLOATS * 4ull) {
        short* ah = (short*)(ws + O_AH);
        short* al = (short*)(ws + O_AL);
        unsigned long long* keys = (unsigned long long*)(ws + O_KEYS);
        hipLaunchKernelGGL(inp_conv, dim3(8192), dim3(256), 0, stream, inp, ah, al);
        hipLaunchKernelGGL(vq_gemm, dim3((NROWS / 128) * 32), dim3(512), 0, stream,
                           ah, al, eh, el, esq, pmin2, pidx);
        hipLaunchKernelGGL(vq_reduce, dim3(NROWS / 256), dim3(256), 0, stream,
                           pmin2, pidx, idx_final, flags, fcount, keys);
        hipLaunchKernelGGL(vq_recheck2, dim3(8192), dim3(256), 0, stream,
                           inp, emb, esq, flags, fcount, keys);
        hipLaunchKernelGGL(vq_unpack, dim3(NROWS / 256), dim3(256), 0, stream,
                           flags, fcount, keys, idx_final);
    } else {
        hipLaunchKernelGGL(vq_gemm_fb, dim3((NROWS / 128) * 32), dim3(256), 0, stream,
                           inp, eh, el, esq, pmin2, pidx);
        hipLaunchKernelGGL(vq_reduce, dim3(NROWS / 256), dim3(256), 0, stream,
                           pmin2, pidx, idx_final, flags, fcount,
                           (unsigned long long*)nullptr);
        hipLaunchKernelGGL(vq_recheck, dim3(256), dim3(256), 0, stream,
                           inp, emb, esq, flags, fcount, idx_final);
    }

    hipLaunchKernelGGL(vq_gather, dim3(NLBLK), dim3(256), 0, stream,
                       inp, emb, idx_final, out, loss_part);
    hipLaunchKernelGGL(loss_kernel, dim3(1), dim3(256), 0, stream, loss_part, out);
}

// Round 12
// 664.049 us; speedup vs baseline: 1.3775x; 1.0142x over previous
//
#include <hip/hip_runtime.h>
#include <float.h>
#include <stdint.h>

// VectorQuantizer R18: R17 (673us) + two exact tail cuts:
//  (a) GEMM epilogue wn-merge: wn=0/1 waves cover identical rows; merge
//      their (m1,m2,bi) via LDS scratch (Ah/Al/Bh reuse after barrier),
//      replicating vq_reduce's sequential merge step in old slot order
//      (ni*2+0 then ni*2+1) -> slots 64->32, pmin2/pidx traffic halved,
//      flags/indices bit-identical (top-2-of-multiset + earlier-slot tie
//      rule is associative under pair grouping).
//  (b) esq_conv + inp_conv fused into one launch (prep_conv).
//  GEMM core verbatim R14/R17 (proven 496-525us, 0 conflicts).
// d_out = [quantized 16777216 f32][loss 1][indices 65536] ; scratch reuse:
//   pmin2 = 32 slots x float2 x 65536 rows (16.8MB) at out[0,4194304) fl,
//   pidx 32 x int x 65536 (8.4MB) at out+4194304 (both overwritten later).
// d_ws floats: esq[0,4096) | fcount@4097 | flags@4100 | idx_final@69636 |
//   loss_part@135172 | emb_hi@151556 | emb_lo@675844 | a_hi@1200384 |
//   a_lo@9588992 | keys@17977600 (u64 x 65536) -> end 18108672 fl = 72.4MB

#define DDIM 256
#define KCODES 4096
#define NROWS 65536
#define QSIZE 16777216
#define NSLOT 32
#define NSLOT_FB 64
#define NLBLK 16384
#define GAP_THRESH 0.02f

#define O_FCOUNT 4097
#define O_FLAGS 4100
#define O_IDXF 69636
#define O_LPART 135172
#define O_EMBH 151556
#define O_EMBL 675844
#define O_AH 1200384
#define O_AL 9588992
#define O_KEYS 17977600
#define WS_NEED_FLOATS 18108672ull

typedef short bf16x8 __attribute__((ext_vector_type(8)));
typedef float f32x4 __attribute__((ext_vector_type(4)));

__device__ __forceinline__ void gload_lds16(const void* g, void* l) {
    __builtin_amdgcn_global_load_lds(
        (const __attribute__((address_space(1))) void*)g,
        (__attribute__((address_space(3))) void*)l, 16, 0, 0);
}

// split fp32 -> (hi bf16, lo bf16), pack 8 elems, write 16B hi + 16B lo
__device__ __forceinline__ void conv8(float4 a, float4 b,
                                      short* __restrict__ dh,
                                      short* __restrict__ dl) {
    float f[8] = {a.x, a.y, a.z, a.w, b.x, b.y, b.z, b.w};
    uint32_t hu[8], lu[8];
#pragma unroll
    for (int k = 0; k < 8; ++k) {
        uint32_t u = __float_as_uint(f[k]);
        uint32_t h = u & 0xFFFF0000u;
        hu[k] = h;
        lu[k] = __float_as_uint(f[k] - __uint_as_float(h));
    }
    uint4 hv, lv;
    hv.x = __builtin_amdgcn_perm(hu[1], hu[0], 0x07060302u);
    hv.y = __builtin_amdgcn_perm(hu[3], hu[2], 0x07060302u);
    hv.z = __builtin_amdgcn_perm(hu[5], hu[4], 0x07060302u);
    hv.w = __builtin_amdgcn_perm(hu[7], hu[6], 0x07060302u);
    lv.x = __builtin_amdgcn_perm(lu[1], lu[0], 0x07060302u);
    lv.y = __builtin_amdgcn_perm(lu[3], lu[2], 0x07060302u);
    lv.z = __builtin_amdgcn_perm(lu[5], lu[4], 0x07060302u);
    lv.w = __builtin_amdgcn_perm(lu[7], lu[6], 0x07060302u);
    *(uint4*)dh = hv;
    *(uint4*)dl = lv;
}

__device__ __forceinline__ void stage8(const float* __restrict__ p,
                                       short* __restrict__ dh,
                                       short* __restrict__ dl) {
    float4 a = *(const float4*)p;
    float4 b = *(const float4*)(p + 4);
    conv8(a, b, dh, dl);
}

// ---- esq-only kernel (fallback path) ----
__global__ __launch_bounds__(64) void esq_conv(const float* __restrict__ emb,
                                               float* __restrict__ ws,
                                               short* __restrict__ eh,
                                               short* __restrict__ el) {
    int c = blockIdx.x, l = threadIdx.x;
    const float4* e4 = (const float4*)(emb + (size_t)c * DDIM);
    float4 v = e4[l];
    float s = v.x * v.x + v.y * v.y + v.z * v.z + v.w * v.w;
    float f[4] = {v.x, v.y, v.z, v.w};
    uint32_t hu[4], lu[4];
#pragma unroll
    for (int k = 0; k < 4; ++k) {
        uint32_t u = __float_as_uint(f[k]);
        uint32_t h = u & 0xFFFF0000u;
        hu[k] = h;
        lu[k] = __float_as_uint(f[k] - __uint_as_float(h));
    }
    uint2 hv, lv;
    hv.x = __builtin_amdgcn_perm(hu[1], hu[0], 0x07060302u);
    hv.y = __builtin_amdgcn_perm(hu[3], hu[2], 0x07060302u);
    lv.x = __builtin_amdgcn_perm(lu[1], lu[0], 0x07060302u);
    lv.y = __builtin_amdgcn_perm(lu[3], lu[2], 0x07060302u);
    *(uint2*)&eh[(size_t)c * DDIM + l * 4] = hv;
    *(uint2*)&el[(size_t)c * DDIM + l * 4] = lv;
#pragma unroll
    for (int off = 32; off >= 1; off >>= 1) s += __shfl_down(s, off);
    if (l == 0) ws[c] = s;
    if (c == 0 && l == 0) ((int*)ws)[O_FCOUNT] = 0;
}

// ---- fused prep: blocks [0,8192) convert inp; [8192,9216) do esq/emb ----
__global__ __launch_bounds__(256) void prep_conv(const float* __restrict__ inp,
                                                 const float* __restrict__ emb,
                                                 float* __restrict__ ws,
                                                 short* __restrict__ eh,
                                                 short* __restrict__ el,
                                                 short* __restrict__ ahg,
                                                 short* __restrict__ alg) {
    int b = blockIdx.x, t = threadIdx.x;
    if (b < 8192) {
        size_t g = (size_t)b * 256 + t;           // granule of 8 elems
        const float* p = inp + g * 8;
        float4 a = *(const float4*)p;
        float4 bb = *(const float4*)(p + 4);
        conv8(a, bb, ahg + g * 8, alg + g * 8);
        return;
    }
    int c = (b - 8192) * 4 + (t >> 6);            // 4 codes per block
    int l = t & 63;
    const float4* e4 = (const float4*)(emb + (size_t)c * DDIM);
    float4 v = e4[l];
    float s = v.x * v.x + v.y * v.y + v.z * v.z + v.w * v.w;
    float f[4] = {v.x, v.y, v.z, v.w};
    uint32_t hu[4], lu[4];
#pragma unroll
    for (int k = 0; k < 4; ++k) {
        uint32_t u = __float_as_uint(f[k]);
        uint32_t h = u & 0xFFFF0000u;
        hu[k] = h;
        lu[k] = __float_as_uint(f[k] - __uint_as_float(h));
    }
    uint2 hv, lv;
    hv.x = __builtin_amdgcn_perm(hu[1], hu[0], 0x07060302u);
    hv.y = __builtin_amdgcn_perm(hu[3], hu[2], 0x07060302u);
    lv.x = __builtin_amdgcn_perm(lu[1], lu[0], 0x07060302u);
    lv.y = __builtin_amdgcn_perm(lu[3], lu[2], 0x07060302u);
    *(uint2*)&eh[(size_t)c * DDIM + l * 4] = hv;
    *(uint2*)&el[(size_t)c * DDIM + l * 4] = lv;
#pragma unroll
    for (int off = 32; off >= 1; off >>= 1) s += __shfl_down(s, off);
    if (l == 0) ws[c] = s;
    if (c == 0 && l == 0) ((int*)ws)[O_FCOUNT] = 0;
}

// ---- main GEMM: 128x128 tile, 512 thr (8 waves 4Mx2N), 8 chunks ----
// Core verbatim R14/R17 (proven 496-525us, 0 conflicts). Epilogue: wn-merge
// via LDS scratch -> one slot per ni (32 slots).
__global__ __launch_bounds__(512, 6) void vq_gemm(const short* __restrict__ ahg,
                                                  const short* __restrict__ alg,
                                                  const short* __restrict__ ehg,
                                                  const short* __restrict__ elg,
                                                  const float* __restrict__ esq,
                                                  float2* __restrict__ pmin2,
                                                  int* __restrict__ pidx) {
    __shared__ __align__(16) short Ah[128 * 32];  // 8 KB each, 32 KB total
    __shared__ __align__(16) short Al[128 * 32];
    __shared__ __align__(16) short Bh[128 * 32];
    __shared__ __align__(16) short Bl[128 * 32];

    const int t = threadIdx.x;                    // 0..511
    const int mi = blockIdx.x >> 5, ni = blockIdx.x & 31;
    const size_t row0 = (size_t)mi * 128;
    const int col0 = ni * 128;
    const int lane = t & 63, wave = t >> 6;       // wave 0..7
    const int wm = wave >> 1, wn = wave & 1;      // 4 M-waves x 2 N-waves
    const int n15 = lane & 15, quad = lane >> 4;
    const int swz = (n15 >> 1) & 3;

    // staging: 1 granule (8 elems = 16B) per thread per matrix
    const int r0 = t >> 2, c0 = t & 3;
    const int p0 = c0 ^ ((r0 >> 1) & 3);
    const short* asrch = ahg + (size_t)(row0 + r0) * DDIM + p0 * 8;
    const short* asrcl = alg + (size_t)(row0 + r0) * DDIM + p0 * 8;
    const short* bsrch = ehg + (size_t)(col0 + r0) * DDIM + p0 * 8;
    const short* bsrcl = elg + (size_t)(col0 + r0) * DDIM + p0 * 8;
    const int d0 = t * 8;                         // linear LDS dest

    f32x4 acc[2][4];
#pragma unroll
    for (int i = 0; i < 2; ++i)
#pragma unroll
        for (int j = 0; j < 4; ++j) {
            acc[i][j][0] = 0.f; acc[i][j][1] = 0.f;
            acc[i][j][2] = 0.f; acc[i][j][3] = 0.f;
        }

#pragma unroll
    for (int ch = 0; ch < 8; ++ch) {
        __syncthreads();  // prior chunk's LDS reads complete
        gload_lds16(asrch + ch * 32, &Ah[d0]);
        gload_lds16(asrcl + ch * 32, &Al[d0]);
        gload_lds16(bsrch + ch * 32, &Bh[d0]);
        gload_lds16(bsrcl + ch * 32, &Bl[d0]);
        __syncthreads();  // drains vmcnt -> tiles visible

        bf16x8 ah[2], al[2];
#pragma unroll
        for (int i = 0; i < 2; ++i) {
            int off = (wm * 32 + i * 16 + n15) * 32 + ((quad ^ swz) * 8);
            ah[i] = *(const bf16x8*)&Ah[off];
            al[i] = *(const bf16x8*)&Al[off];
        }
#pragma unroll
        for (int j = 0; j < 4; ++j) {
            int boff = (wn * 64 + j * 16 + n15) * 32 + ((quad ^ swz) * 8);
            bf16x8 bh = *(const bf16x8*)&Bh[boff];
            bf16x8 bl = *(const bf16x8*)&Bl[boff];
#pragma unroll
            for (int i = 0; i < 2; ++i) {
                acc[i][j] = __builtin_amdgcn_mfma_f32_16x16x32_bf16(ah[i], bh, acc[i][j], 0, 0, 0);
                acc[i][j] = __builtin_amdgcn_mfma_f32_16x16x32_bf16(ah[i], bl, acc[i][j], 0, 0, 0);
                acc[i][j] = __builtin_amdgcn_mfma_f32_16x16x32_bf16(al[i], bh, acc[i][j], 0, 0, 0);
            }
        }
    }

    // ---- epilogue: per-wave top-2 over its 64 codes (R4 semantics) ----
    float esqv[4];
#pragma unroll
    for (int j = 0; j < 4; ++j) esqv[j] = esq[col0 + wn * 64 + j * 16 + n15];

    float fm1[8], fm2[8];
    int fbi[8];
#pragma unroll
    for (int i = 0; i < 2; ++i) {
#pragma unroll
        for (int reg = 0; reg < 4; ++reg) {
            float m1 = FLT_MAX, m2 = FLT_MAX;
            int bi = 0;
#pragma unroll
            for (int j = 0; j < 4; ++j) {
                float d = esqv[j] - 2.0f * acc[i][j][reg];
                int code = col0 + wn * 64 + j * 16 + n15;
                if (d < m1) { m2 = m1; m1 = d; bi = code; }
                else if (d < m2) { m2 = d; }
            }
#pragma unroll
            for (int off = 1; off < 16; off <<= 1) {
                float om1 = __shfl_xor(m1, off);
                float om2 = __shfl_xor(m2, off);
                int obi = __shfl_xor(bi, off);
                bool take = (om1 < m1) || (om1 == m1 && obi < bi);
                if (take) { m2 = fminf(m1, om2); m1 = om1; bi = obi; }
                else      { m2 = fminf(om1, m2); }
            }
            fm1[i * 4 + reg] = m1;
            fm2[i * 4 + reg] = m2;
            fbi[i * 4 + reg] = bi;
        }
    }

    // wn-merge via LDS scratch (reuse Ah/Al/Bh). Slot order preserved:
    // wn=0 (old slot ni*2+0) is the base, wn=1 (ni*2+1) merged second via
    // the exact vq_reduce step -> bit-identical (m1,m2,bi) per row.
    float* s1 = (float*)Ah;   // 128 floats used
    float* s2 = (float*)Al;
    int* sb = (int*)Bh;
    __syncthreads();          // all LDS tile reads complete before reuse
    if (wn == 1 && n15 == 0) {
#pragma unroll
        for (int k = 0; k < 8; ++k) {
            int local = (k >> 2) * 16 + quad * 4 + (k & 3);
            int s = wm * 32 + local;
            s1[s] = fm1[k]; s2[s] = fm2[k]; sb[s] = fbi[k];
        }
    }
    __syncthreads();
    if (wn == 0 && n15 == 0) {
#pragma unroll
        for (int k = 0; k < 8; ++k) {
            int local = (k >> 2) * 16 + quad * 4 + (k & 3);
            int s = wm * 32 + local;
            float m1 = fm1[k], m2 = fm2[k];
            int bi = fbi[k];
            float p1 = s1[s], p2 = s2[s];
            int pb = sb[s];
            if (p1 < m1) { m2 = fminf(m1, p2); m1 = p1; bi = pb; }
            else         { m2 = fminf(m2, p1); }
            int rg = (int)row0 + wm * 32 + local;
            pmin2[(size_t)ni * NROWS + rg] = make_float2(m1, m2);
            pidx[(size_t)ni * NROWS + rg] = bi;
        }
    }
}

// ---- fallback GEMM (R6 verbatim): in-kernel A conversion, small ws ----
__global__ __launch_bounds__(256, 2) void vq_gemm_fb(const float* __restrict__ inp,
                                                     const short* __restrict__ ehg,
                                                     const short* __restrict__ elg,
                                                     const float* __restrict__ esq,
                                                     float2* __restrict__ pmin2,
                                                     int* __restrict__ pidx) {
    __shared__ __align__(16) short Ah[128 * 32];
    __shared__ __align__(16) short Al[128 * 32];
    __shared__ __align__(16) short Bh[128 * 32];
    __shared__ __align__(16) short Bl[128 * 32];

    const int t = threadIdx.x;
    const int mi = blockIdx.x >> 5, ni = blockIdx.x & 31;
    const size_t row0 = (size_t)mi * 128;
    const int col0 = ni * 128;
    const int lane = t & 63, wave = t >> 6;
    const int wm = wave >> 1, wn = wave & 1;
    const int n15 = lane & 15, quad = lane >> 4;
    const int swz = (n15 >> 1) & 3;

    const int ar0 = t >> 2, ac0 = t & 3;
    const int ap0 = ac0 ^ ((ar0 >> 1) & 3);
    const int ar1 = (t + 256) >> 2, ac1 = ac0;
    const int ap1 = ac1 ^ ((ar1 >> 1) & 3);
    const float* asrc0 = inp + (row0 + ar0) * DDIM + ac0 * 8;
    const float* asrc1 = inp + (row0 + ar1) * DDIM + ac1 * 8;
    short* adst0h = &Ah[ar0 * 32 + ap0 * 8];
    short* adst0l = &Al[ar0 * 32 + ap0 * 8];
    short* adst1h = &Ah[ar1 * 32 + ap1 * 8];
    short* adst1l = &Al[ar1 * 32 + ap1 * 8];
    const int br0 = ar0, bp0 = ac0, bk0 = bp0 ^ ((br0 >> 1) & 3);
    const int br1 = ar1, bp1 = ac1, bk1 = bp1 ^ ((br1 >> 1) & 3);
    const short* bsrc0h = ehg + (size_t)(col0 + br0) * DDIM + bk0 * 8;
    const short* bsrc0l = elg + (size_t)(col0 + br0) * DDIM + bk0 * 8;
    const short* bsrc1h = ehg + (size_t)(col0 + br1) * DDIM + bk1 * 8;
    const short* bsrc1l = elg + (size_t)(col0 + br1) * DDIM + bk1 * 8;

    f32x4 acc[4][4];
#pragma unroll
    for (int i = 0; i < 4; ++i)
#pragma unroll
        for (int j = 0; j < 4; ++j) {
            acc[i][j][0] = 0.f; acc[i][j][1] = 0.f;
            acc[i][j][2] = 0.f; acc[i][j][3] = 0.f;
        }

#pragma unroll
    for (int ch = 0; ch < 8; ++ch) {
        __syncthreads();
        gload_lds16(bsrc0h + ch * 32, &Bh[t * 8]);
        gload_lds16(bsrc0l + ch * 32, &Bl[t * 8]);
        gload_lds16(bsrc1h + ch * 32, &Bh[(t + 256) * 8]);
        gload_lds16(bsrc1l + ch * 32, &Bl[(t + 256) * 8]);
        stage8(asrc0 + ch * 32, adst0h, adst0l);
        stage8(asrc1 + ch * 32, adst1h, adst1l);
        __syncthreads();

        bf16x8 ah[4], al[4];
#pragma unroll
        for (int i = 0; i < 4; ++i) {
            int off = (wm * 64 + i * 16 + n15) * 32 + ((quad ^ swz) * 8);
            ah[i] = *(const bf16x8*)&Ah[off];
            al[i] = *(const bf16x8*)&Al[off];
        }
#pragma unroll
        for (int j = 0; j < 4; ++j) {
            int boff = (wn * 64 + j * 16 + n15) * 32 + ((quad ^ swz) * 8);
            bf16x8 bh = *(const bf16x8*)&Bh[boff];
            bf16x8 bl = *(const bf16x8*)&Bl[boff];
#pragma unroll
            for (int i = 0; i < 4; ++i) {
                acc[i][j] = __builtin_amdgcn_mfma_f32_16x16x32_bf16(ah[i], bh, acc[i][j], 0, 0, 0);
                acc[i][j] = __builtin_amdgcn_mfma_f32_16x16x32_bf16(ah[i], bl, acc[i][j], 0, 0, 0);
                acc[i][j] = __builtin_amdgcn_mfma_f32_16x16x32_bf16(al[i], bh, acc[i][j], 0, 0, 0);
            }
        }
    }

    float esqv[4];
#pragma unroll
    for (int j = 0; j < 4; ++j) esqv[j] = esq[col0 + wn * 64 + j * 16 + n15];

#pragma unroll
    for (int i = 0; i < 4; ++i) {
#pragma unroll
        for (int reg = 0; reg < 4; ++reg) {
            float m1 = FLT_MAX, m2 = FLT_MAX;
            int bi = 0;
#pragma unroll
            for (int j = 0; j < 4; ++j) {
                float d = esqv[j] - 2.0f * acc[i][j][reg];
                int code = col0 + wn * 64 + j * 16 + n15;
                if (d < m1) { m2 = m1; m1 = d; bi = code; }
                else if (d < m2) { m2 = d; }
            }
#pragma unroll
            for (int off = 1; off < 16; off <<= 1) {
                float om1 = __shfl_xor(m1, off);
                float om2 = __shfl_xor(m2, off);
                int obi = __shfl_xor(bi, off);
                bool take = (om1 < m1) || (om1 == m1 && obi < bi);
                if (take) { m2 = fminf(m1, om2); m1 = om1; bi = obi; }
                else      { m2 = fminf(om1, m2); }
            }
            if (n15 == 0) {
                int rg = (int)row0 + wm * 64 + i * 16 + quad * 4 + reg;
                int slot = ni * 2 + wn;
                pmin2[(size_t)slot * NROWS + rg] = make_float2(m1, m2);
                pidx[(size_t)slot * NROWS + rg] = bi;
            }
        }
    }
}

// ---- reduce 32 merged partials per row; flag near-ties (+key init) ----
__global__ __launch_bounds__(256) void vq_reduce(const float2* __restrict__ pmin2,
                                                 const int* __restrict__ pidx,
                                                 int* __restrict__ idx_final,
                                                 int* __restrict__ flags,
                                                 int* __restrict__ fcount,
                                                 unsigned long long* __restrict__ keys) {
    int row = blockIdx.x * 256 + threadIdx.x;
    float m1 = FLT_MAX, m2 = FLT_MAX;
    int bi = 0;
    for (int nb = 0; nb < NSLOT; ++nb) {
        float2 p = pmin2[(size_t)nb * NROWS + row];
        int pi = pidx[(size_t)nb * NROWS + row];
        if (p.x < m1) { m2 = fminf(m1, p.y); m1 = p.x; bi = pi; }
        else          { m2 = fminf(m2, p.x); }
    }
    idx_final[row] = bi;
    if (m2 - m1 < GAP_THRESH) {
        int s = atomicAdd(fcount, 1);
        flags[s] = row;
        keys[s] = 0xFFFFFFFFFFFFFFFFull;
    }
}

// ---- fallback reduce: 64 slots, no keys ----
__global__ __launch_bounds__(256) void vq_reduce_fb(const float2* __restrict__ pmin2,
                                                    const int* __restrict__ pidx,
                                                    int* __restrict__ idx_final,
                                                    int* __restrict__ flags,
                                                    int* __restrict__ fcount) {
    int row = blockIdx.x * 256 + threadIdx.x;
    float m1 = FLT_MAX, m2 = FLT_MAX;
    int bi = 0;
    for (int nb = 0; nb < NSLOT_FB; ++nb) {
        float2 p = pmin2[(size_t)nb * NROWS + row];
        int pi = pidx[(size_t)nb * NROWS + row];
        if (p.x < m1) { m2 = fminf(m1, p.y); m1 = p.x; bi = pi; }
        else          { m2 = fminf(m2, p.x); }
    }
    idx_final[row] = bi;
    if (m2 - m1 < GAP_THRESH) {
        int s = atomicAdd(fcount, 1);
        flags[s] = row;
    }
}

// ---- fast fp32 recheck: 4 rows batched per block iteration, 1 code/thr ----
__global__ __launch_bounds__(256) void vq_recheck2(const float* __restrict__ inp,
                                                   const float* __restrict__ emb,
                                                   const float* __restrict__ esq,
                                                   const int* __restrict__ flags,
                                                   const int* __restrict__ fcount,
                                                   unsigned long long* __restrict__ keys) {
    __shared__ float4 xs[4][64];
    __shared__ unsigned long long wbest[4][4];   // [wave][row-in-group]
    const int t = threadIdx.x;
    const int cnt = *fcount;
    const int ngrp = (cnt + 3) >> 2;
    const int total = ngrp * 16;
    for (int wi = blockIdx.x; wi < total; wi += gridDim.x) {
        const int gi = wi >> 4, cb = wi & 15;
        const int base = gi * 4;
        const int nr = (cnt - base < 4) ? (cnt - base) : 4;
        __syncthreads();
        {
            int rr = t >> 6, l = t & 63;          // 4 rows x 64 lanes = 256
            if (rr < nr)
                xs[rr][l] = ((const float4*)inp)[(size_t)flags[base + rr] * 64 + l];
        }
        __syncthreads();
        const int c = cb * 256 + t;
        const float4* e4 = (const float4*)emb + (size_t)c * 64;
        float dot0 = 0.f, dot1 = 0.f, dot2 = 0.f, dot3 = 0.f;
        for (int d4 = 0; d4 < 64; ++d4) {
            float4 e = e4[d4];
            float4 x0 = xs[0][d4];
            float4 x1 = xs[1][d4];
            float4 x2 = xs[2][d4];
            float4 x3 = xs[3][d4];
            dot0 += e.x * x0.x; dot0 += e.y * x0.y; dot0 += e.z * x0.z; dot0 += e.w * x0.w;
            dot1 += e.x * x1.x; dot1 += e.y * x1.y; dot1 += e.z * x1.z; dot1 += e.w * x1.w;
            dot2 += e.x * x2.x; dot2 += e.y * x2.y; dot2 += e.z * x2.z; dot2 += e.w * x2.w;
            dot3 += e.x * x3.x; dot3 += e.y * x3.y; dot3 += e.z * x3.z; dot3 += e.w * x3.w;
        }
        float dts[4] = {dot0, dot1, dot2, dot3};
        const float ec = esq[c];
#pragma unroll
        for (int rr = 0; rr < 4; ++rr) {
            float d = ec - 2.0f * dts[rr];
            unsigned u = __float_as_uint(d);
            unsigned skey = (u & 0x80000000u) ? ~u : (u | 0x80000000u);
            unsigned long long k = ((unsigned long long)skey << 32) | (unsigned)c;
#pragma unroll
            for (int off = 1; off < 64; off <<= 1) {
                unsigned long long o = __shfl_xor(k, off);
                if (o < k) k = o;
            }
            if ((t & 63) == 0) wbest[t >> 6][rr] = k;
        }
        __syncthreads();
        if (t < nr) {
            unsigned long long b = wbest[0][t];
            if (wbest[1][t] < b) b = wbest[1][t];
            if (wbest[2][t] < b) b = wbest[2][t];
            if (wbest[3][t] < b) b = wbest[3][t];
            atomicMin(&keys[base + t], b);
        }
    }
}

__global__ __launch_bounds__(256) void vq_unpack(const int* __restrict__ flags,
                                                 const int* __restrict__ fcount,
                                                 const unsigned long long* __restrict__ keys,
                                                 int* __restrict__ idx_final) {
    int i = blockIdx.x * 256 + threadIdx.x;
    if (i < *fcount) idx_final[flags[i]] = (int)(keys[i] & 0xFFFFFFFFull);
}

// ---- original serial recheck (fallback path only) ----
__global__ __launch_bounds__(256) void vq_recheck(const float* __restrict__ inp,
                                                  const float* __restrict__ emb,
                                                  const float* __restrict__ esq,
                                                  const int* __restrict__ flags,
                                                  const int* __restrict__ fcount,
                                                  int* __restrict__ idx_final) {
    __shared__ float4 xs[64];
    __shared__ float sv[4];
    __shared__ int si[4];
    const int t = threadIdx.x;
    const int cnt = *fcount;
    for (int f = blockIdx.x; f < cnt; f += gridDim.x) {
        int row = flags[f];
        __syncthreads();
        if (t < 64) xs[t] = ((const float4*)inp)[(size_t)row * 64 + t];
        __syncthreads();
        float m1 = FLT_MAX;
        int bi = 0x7FFFFFFF;
        for (int cc = 0; cc < 16; ++cc) {
            int c = cc * 256 + t;
            const float4* e4 = (const float4*)emb + (size_t)c * 64;
            float dot = 0.f;
            for (int d4 = 0; d4 < 64; ++d4) {
                float4 e = e4[d4];
                float4 x = xs[d4];
                dot += e.x * x.x; dot += e.y * x.y;
                dot += e.z * x.z; dot += e.w * x.w;
            }
            float d = esq[c] - 2.0f * dot;
            if (d < m1 || (d == m1 && c < bi)) { m1 = d; bi = c; }
        }
#pragma unroll
        for (int off = 1; off < 64; off <<= 1) {
            float om = __shfl_xor(m1, off);
            int ob = __shfl_xor(bi, off);
            if (om < m1 || (om == m1 && ob < bi)) { m1 = om; bi = ob; }
        }
        if ((t & 63) == 0) { sv[t >> 6] = m1; si[t >> 6] = bi; }
        __syncthreads();
        if (t == 0) {
            for (int w = 1; w < 4; ++w)
                if (sv[w] < m1 || (sv[w] == m1 && si[w] < bi)) { m1 = sv[w]; bi = si[w]; }
            idx_final[row] = bi;
        }
    }
}

// ---- gather quantized, write indices, per-block loss partial ----
__global__ __launch_bounds__(256) void vq_gather(const float* __restrict__ inp,
                                                 const float* __restrict__ emb,
                                                 const int* __restrict__ idx_final,
                                                 float* __restrict__ out,
                                                 float* __restrict__ loss_part) {
    __shared__ float wsum[4];
    size_t gid = (size_t)blockIdx.x * 256 + threadIdx.x;
    int row = (int)(gid >> 6), c4 = (int)(gid & 63);
    int k = idx_final[row];
    float4 e = ((const float4*)emb)[(size_t)k * 64 + c4];
    float4 x = ((const float4*)inp)[gid];
    ((float4*)out)[gid] = e;
    float dx = e.x - x.x, dy = e.y - x.y, dz = e.z - x.z, dw = e.w - x.w;
    float ls = dx * dx + dy * dy + dz * dz + dw * dw;
#pragma unroll
    for (int off = 32; off >= 1; off >>= 1) ls += __shfl_down(ls, off);
    if ((threadIdx.x & 63) == 0) wsum[threadIdx.x >> 6] = ls;
    if (c4 == 0) out[(size_t)QSIZE + 1 + row] = (float)k;
    __syncthreads();
    if (threadIdx.x == 0)
        loss_part[blockIdx.x] = wsum[0] + wsum[1] + wsum[2] + wsum[3];
}

__global__ __launch_bounds__(256) void loss_kernel(const float* __restrict__ loss_part,
                                                   float* __restrict__ out) {
    __shared__ float sw[4];
    int t = threadIdx.x;
    float s = 0.0f;
    for (int i = t; i < NLBLK; i += 256) s += loss_part[i];
#pragma unroll
    for (int off = 32; off >= 1; off >>= 1) s += __shfl_down(s, off);
    if ((t & 63) == 0) sw[t >> 6] = s;
    __syncthreads();
    if (t == 0)
        out[QSIZE] = (sw[0] + sw[1] + sw[2] + sw[3]) * (1.0f / 16777216.0f);
}

extern "C" void kernel_launch(void* const* d_in, const int* in_sizes, int n_in,
                              void* d_out, int out_size, void* d_ws, size_t ws_size,
                              hipStream_t stream) {
    const float* inp = (const float*)d_in[0];
    const float* emb = (const float*)d_in[1];
    float* out = (float*)d_out;
    float* ws = (float*)d_ws;

    float* esq = ws;
    int* fcount = (int*)ws + O_FCOUNT;
    int* flags = (int*)ws + O_FLAGS;
    int* idx_final = (int*)ws + O_IDXF;
    float* loss_part = ws + O_LPART;
    short* eh = (short*)(ws + O_EMBH);
    short* el = (short*)(ws + O_EMBL);

    if (ws_size >= WS_NEED_FLOATS * 4ull) {
        short* ah = (short*)(ws + O_AH);
        short* al = (short*)(ws + O_AL);
        unsigned long long* keys = (unsigned long long*)(ws + O_KEYS);
        // 32-slot partials in d_out's quantized region
        float2* pmin2 = (float2*)out;             // [0, 4194304) floats
        int* pidx = (int*)out + 4194304;          // [4194304, 6291456)
        hipLaunchKernelGGL(prep_conv, dim3(8192 + KCODES / 4), dim3(256), 0, stream,
                           inp, emb, ws, eh, el, ah, al);
        hipLaunchKernelGGL(vq_gemm, dim3((NROWS / 128) * 32), dim3(512), 0, stream,
                           ah, al, eh, el, esq, pmin2, pidx);
        hipLaunchKernelGGL(vq_reduce, dim3(NROWS / 256), dim3(256), 0, stream,
                           pmin2, pidx, idx_final, flags, fcount, keys);
        hipLaunchKernelGGL(vq_recheck2, dim3(8192), dim3(256), 0, stream,
                           inp, emb, esq, flags, fcount, keys);
        hipLaunchKernelGGL(vq_unpack, dim3(NROWS / 256), dim3(256), 0, stream,
                           flags, fcount, keys, idx_final);
    } else {
        // fallback: 64-slot partials at old offsets
        float2* pmin2 = (float2*)out;             // [0, 8388608) floats
        int* pidx = (int*)out + 8388608;          // [8388608, 12582912)
        hipLaunchKernelGGL(esq_conv, dim3(KCODES), dim3(64), 0, stream, emb, ws, eh, el);
        hipLaunchKernelGGL(vq_gemm_fb, dim3((NROWS / 128) * 32), dim3(256), 0, stream,
                           inp, eh, el, esq, pmin2, pidx);
        hipLaunchKernelGGL(vq_reduce_fb, dim3(NROWS / 256), dim3(256), 0, stream,
                           pmin2, pidx, idx_final, flags, fcount);
        hipLaunchKernelGGL(vq_recheck, dim3(256), dim3(256), 0, stream,
                           inp, emb, esq, flags, fcount, idx_final);
    }

    hipLaunchKernelGGL(vq_gather, dim3(NLBLK), dim3(256), 0, stream,
                       inp, emb, idx_final, out, loss_part);
    hipLaunchKernelGGL(loss_kernel, dim3(1), dim3(256), 0, stream, loss_part, out);
}